// Round 1
// baseline (3305.478 us; speedup 1.0000x reference)
//
#include <hip/hip_runtime.h>

// VQ codebook nearest-neighbor: xs [32768,512] f32, W [8192,512] f32
// out[i] = W[argmin_j ||xs_i - W_j||^2]  (straight-through forward value)
//
// Round 1: exact fp32 register-tiled fused distance+argmin baseline.
//   dist-equivalent score: wnorm[j] - 2 * <x_i, w_j>  (||x||^2 dropped — row-constant)
// Roadmap: R2 = fp16 split-3 MFMA (fp32-accurate at matrix-core rate).

#define M_TOK 32768
#define N_EMB 8192
#define D_K   512

#define BM 128
#define BN 128
#define BK 16
#define LDPAD (BM + 4)          // +4 floats keeps 16B alignment for ds_read_b128
#define S_SPLIT 4               // split code dim across blocks for occupancy
#define CODES_PER_SPLIT (N_EMB / S_SPLIT)       // 2048
#define TILES_PER_SPLIT (CODES_PER_SPLIT / BN)  // 16

// ---------------- wnorm: ||w_j||^2 ----------------
__global__ __launch_bounds__(256) void wnorm_kernel(const float* __restrict__ w,
                                                    float* __restrict__ wnorm) {
  int row  = (blockIdx.x * 256 + threadIdx.x) >> 6;   // one wave per row
  int lane = threadIdx.x & 63;
  if (row >= N_EMB) return;
  const float4* wr = (const float4*)(w + (size_t)row * D_K);
  float4 v0 = wr[lane * 2], v1 = wr[lane * 2 + 1];
  float s = v0.x*v0.x + v0.y*v0.y + v0.z*v0.z + v0.w*v0.w
          + v1.x*v1.x + v1.y*v1.y + v1.z*v1.z + v1.w*v1.w;
  #pragma unroll
  for (int off = 32; off; off >>= 1) s += __shfl_xor(s, off);
  if (lane == 0) wnorm[row] = s;
}

// ---------------- fused score + running argmin ----------------
__global__ __launch_bounds__(256) void dist_argmin_kernel(
    const float* __restrict__ xs, const float* __restrict__ w,
    const float* __restrict__ wnorm,
    float* __restrict__ pval, int* __restrict__ pidx) {
  __shared__ float As[BK][LDPAD];
  __shared__ float Bs[BK][LDPAD];

  const int tid = threadIdx.x;
  const int tx = tid & 15;        // col group (8 cols each)
  const int ty = tid >> 4;        // row group (8 rows each)
  const int row0 = blockIdx.x * BM;
  const int s = blockIdx.y;
  const int code0 = s * CODES_PER_SPLIT;

  // staging indices: thread loads float4 at (lm, lk)
  const int lm = tid >> 2;        // 0..63
  const int lk = (tid & 3) * 4;   // 0,4,8,12

  float rv[8]; int ri[8];
  #pragma unroll
  for (int i = 0; i < 8; i++) { rv[i] = 3.4e38f; ri[i] = 0x7fffffff; }

  for (int t = 0; t < TILES_PER_SPLIT; ++t) {
    const int col0 = code0 + t * BN;

    float acc[8][8];
    #pragma unroll
    for (int i = 0; i < 8; i++)
      #pragma unroll
      for (int j = 0; j < 8; j++) acc[i][j] = 0.f;

    for (int k0 = 0; k0 < D_K; k0 += BK) {
      float4 a0 = *(const float4*)(xs + (size_t)(row0 + lm)      * D_K + k0 + lk);
      float4 a1 = *(const float4*)(xs + (size_t)(row0 + lm + 64) * D_K + k0 + lk);
      float4 b0 = *(const float4*)(w  + (size_t)(col0 + lm)      * D_K + k0 + lk);
      float4 b1 = *(const float4*)(w  + (size_t)(col0 + lm + 64) * D_K + k0 + lk);
      __syncthreads();   // previous iter's LDS reads done
      As[lk+0][lm]    = a0.x; As[lk+1][lm]    = a0.y; As[lk+2][lm]    = a0.z; As[lk+3][lm]    = a0.w;
      As[lk+0][lm+64] = a1.x; As[lk+1][lm+64] = a1.y; As[lk+2][lm+64] = a1.z; As[lk+3][lm+64] = a1.w;
      Bs[lk+0][lm]    = b0.x; Bs[lk+1][lm]    = b0.y; Bs[lk+2][lm]    = b0.z; Bs[lk+3][lm]    = b0.w;
      Bs[lk+0][lm+64] = b1.x; Bs[lk+1][lm+64] = b1.y; Bs[lk+2][lm+64] = b1.z; Bs[lk+3][lm+64] = b1.w;
      __syncthreads();

      #pragma unroll
      for (int kk = 0; kk < BK; kk++) {
        float a[8], b[8];
        *(float4*)&a[0] = *(const float4*)&As[kk][ty * 8];
        *(float4*)&a[4] = *(const float4*)&As[kk][ty * 8 + 4];
        *(float4*)&b[0] = *(const float4*)&Bs[kk][tx * 8];
        *(float4*)&b[4] = *(const float4*)&Bs[kk][tx * 8 + 4];
        #pragma unroll
        for (int i = 0; i < 8; i++)
          #pragma unroll
          for (int j = 0; j < 8; j++)
            acc[i][j] = fmaf(a[i], b[j], acc[i][j]);
      }
    }

    // distance + running min (first-occurrence tie-break: strictly-less, or equal+smaller idx)
    #pragma unroll
    for (int j = 0; j < 8; j++) {
      const int c = col0 + tx * 8 + j;
      const float wn = wnorm[c];
      #pragma unroll
      for (int i = 0; i < 8; i++) {
        const float d = wn - 2.f * acc[i][j];
        if (d < rv[i] || (d == rv[i] && c < ri[i])) { rv[i] = d; ri[i] = c; }
      }
    }
  }

  // reduce across the 16 tx-lanes sharing each row (contiguous 16-lane groups in-wave)
  #pragma unroll
  for (int i = 0; i < 8; i++) {
    float v = rv[i]; int ix = ri[i];
    #pragma unroll
    for (int off = 1; off < 16; off <<= 1) {
      float ov = __shfl_xor(v, off);
      int   oi = __shfl_xor(ix, off);
      if (ov < v || (ov == v && oi < ix)) { v = ov; ix = oi; }
    }
    if (tx == 0) {
      const int row = row0 + ty * 8 + i;
      pval[(size_t)row * S_SPLIT + s] = v;
      pidx[(size_t)row * S_SPLIT + s] = ix;
    }
  }
}

// ---------------- combine splits ----------------
__global__ __launch_bounds__(256) void reduce_idx_kernel(const float* __restrict__ pval,
                                                         const int* __restrict__ pidx,
                                                         int* __restrict__ fidx) {
  int i = blockIdx.x * 256 + threadIdx.x;
  if (i >= M_TOK) return;
  float bv = pval[(size_t)i * S_SPLIT];
  int   bi = pidx[(size_t)i * S_SPLIT];
  #pragma unroll
  for (int s = 1; s < S_SPLIT; s++) {
    float v = pval[(size_t)i * S_SPLIT + s];
    int  ix = pidx[(size_t)i * S_SPLIT + s];
    if (v < bv || (v == bv && ix < bi)) { bv = v; bi = ix; }
  }
  fidx[i] = bi;
}

// ---------------- gather: out = xs + (W[idx] - xs)  (mimic ref arithmetic) ----------------
__global__ __launch_bounds__(256) void gather_kernel(const float* __restrict__ xs,
                                                     const float* __restrict__ w,
                                                     const int* __restrict__ fidx,
                                                     float* __restrict__ out) {
  int e = blockIdx.x * 256 + threadIdx.x;     // one float4 each
  int row = e >> 7, off = e & 127;
  float4 xv = ((const float4*)(xs + (size_t)row * D_K))[off];
  float4 wv = ((const float4*)(w  + (size_t)fidx[row] * D_K))[off];
  float4 o;
  o.x = xv.x + (wv.x - xv.x);
  o.y = xv.y + (wv.y - xv.y);
  o.z = xv.z + (wv.z - xv.z);
  o.w = xv.w + (wv.w - xv.w);
  ((float4*)out)[e] = o;
}

extern "C" void kernel_launch(void* const* d_in, const int* in_sizes, int n_in,
                              void* d_out, int out_size, void* d_ws, size_t ws_size,
                              hipStream_t stream) {
  const float* xs = (const float*)d_in[0];
  const float* w  = (const float*)d_in[1];
  float* out = (float*)d_out;

  // workspace layout (~1.2 MB)
  float* wnorm = (float*)d_ws;                 // 8192
  float* pval  = wnorm + N_EMB;                // 32768*S
  int*   pidx  = (int*)(pval + (size_t)M_TOK * S_SPLIT);
  int*   fidx  = pidx + (size_t)M_TOK * S_SPLIT;

  wnorm_kernel<<<N_EMB / 4, 256, 0, stream>>>(w, wnorm);
  dist_argmin_kernel<<<dim3(M_TOK / BM, S_SPLIT), 256, 0, stream>>>(xs, w, wnorm, pval, pidx);
  reduce_idx_kernel<<<M_TOK / 256, 256, 0, stream>>>(pval, pidx, fidx);
  gather_kernel<<<(M_TOK * (D_K / 4)) / 256, 256, 0, stream>>>(xs, w, fidx, out);
}

// Round 2
// 879.980 us; speedup vs baseline: 3.7563x; 3.7563x over previous
//
#include <hip/hip_runtime.h>

// VQ codebook nearest-neighbor: xs [32768,512] f32, W [8192,512] f32
// out[i] = W[argmin_j ||xs_i - W_j||^2]
//
// R2: f16 split-2 (Markidis) MFMA distance kernel.
//   x = xh + xl (f16 hi + f16 residual); x.w ~= xh.wh + xh.wl + xl.wh
//   score = wnorm[j] - 2*dot  (||x||^2 row-constant, dropped)
//   argmin via order-preserving (floatbits, idx) u64 + global atomicMin.
// Fallback: exact fp32 path (R1) if ws_size too small for f16 staging.

#define M_TOK 32768
#define N_EMB 8192
#define D_K   512

typedef _Float16 f16;
typedef __attribute__((ext_vector_type(8))) _Float16 f16x8;
typedef __attribute__((ext_vector_type(4))) _Float16 f16x4;
typedef __attribute__((ext_vector_type(4))) float f32x4;

// ---------------- global->LDS direct (width 16) ----------------
__device__ __forceinline__ void gload16(const void* g, void* l) {
  __builtin_amdgcn_global_load_lds(
      (const __attribute__((address_space(1))) unsigned int*)g,
      (__attribute__((address_space(3))) unsigned int*)l, 16, 0, 0);
}

// ---------------- wnorm: ||w_j||^2 ----------------
__global__ __launch_bounds__(256) void wnorm_kernel(const float* __restrict__ w,
                                                    float* __restrict__ wnorm) {
  int row  = (blockIdx.x * 256 + threadIdx.x) >> 6;
  int lane = threadIdx.x & 63;
  if (row >= N_EMB) return;
  const float4* wr = (const float4*)(w + (size_t)row * D_K);
  float4 v0 = wr[lane * 2], v1 = wr[lane * 2 + 1];
  float s = v0.x*v0.x + v0.y*v0.y + v0.z*v0.z + v0.w*v0.w
          + v1.x*v1.x + v1.y*v1.y + v1.z*v1.z + v1.w*v1.w;
  #pragma unroll
  for (int off = 32; off; off >>= 1) s += __shfl_xor(s, off);
  if (lane == 0) wnorm[row] = s;
}

// ---------------- fp32 -> f16 hi/lo split: dst row = [hi(512) | lo(512)] ----------------
__global__ __launch_bounds__(256) void convert_kernel(const float* __restrict__ src,
                                                      f16* __restrict__ dst, int rows) {
  int e = blockIdx.x * 256 + threadIdx.x;     // one float4 per thread
  if (e >= rows * 128) return;
  int row = e >> 7, c4 = e & 127;
  float4 v = ((const float4*)src)[(size_t)row * 128 + c4];
  f16x4 h, l;
  h.x = (f16)v.x; l.x = (f16)(v.x - (float)h.x);
  h.y = (f16)v.y; l.y = (f16)(v.y - (float)h.y);
  h.z = (f16)v.z; l.z = (f16)(v.z - (float)h.z);
  h.w = (f16)v.w; l.w = (f16)(v.w - (float)h.w);
  *(f16x4*)(dst + (size_t)row * 1024 + c4 * 4)       = h;
  *(f16x4*)(dst + (size_t)row * 1024 + 512 + c4 * 4) = l;
}

// ---------------- init pbest to +inf ----------------
__global__ __launch_bounds__(256) void init_pbest_kernel(unsigned long long* __restrict__ pbest) {
  int i = blockIdx.x * 256 + threadIdx.x;
  if (i < M_TOK) pbest[i] = 0xFFFFFFFFFFFFFFFFULL;
}

// ---------------- MFMA distance + argmin ----------------
// 128x128 tile, 4 waves (2x2), BK=32. LDS: Ah|Al|Bh|Bl each [128][32] f16, XOR-swizzled.
__global__ __launch_bounds__(256, 2) void dist_mfma_kernel(
    const f16* __restrict__ Xc, const f16* __restrict__ Wc,
    const float* __restrict__ wnorm, unsigned long long* __restrict__ pbest) {
  __shared__ f16 smem[4 * 128 * 32];   // 32 KB
  f16* Ah = smem;
  f16* Al = smem + 4096;
  f16* Bh = smem + 8192;
  f16* Bl = smem + 12288;

  int bid = (int)blockIdx.x;
  bid = (bid & 7) * 2048 + (bid >> 3);          // XCD swizzle (16384 % 8 == 0, bijective)
  const int rt = bid >> 6, ct = bid & 63;
  const int row0 = rt * 128, col0 = ct * 128;

  const int tid  = threadIdx.x;
  const int w    = tid >> 6, lane = tid & 63;
  const int wr   = w >> 1,   wc   = w & 1;
  const int g    = lane >> 4, cl  = lane & 15;

  f32x4 acc[4][4];
  #pragma unroll
  for (int i = 0; i < 4; i++)
    #pragma unroll
    for (int j = 0; j < 4; j++) acc[i][j] = (f32x4)(0.0f);

  // staging chunk indices (16B chunks within a tile): c = w*128 + j*64 + lane
  // row = c>>2; source k-granule pre-swizzled: kg = (c&3) ^ ((c>>3)&3)
  const int c0 = w * 128 + lane;

  for (int ks = 0; ks < 16; ++ks) {
    const int k0 = ks * 32;
    #pragma unroll
    for (int j = 0; j < 2; ++j) {
      const int c  = c0 + j * 64;
      const int r  = c >> 2;
      const int kg = ((c & 3) ^ ((c >> 3) & 3)) * 8;   // pre-swizzled source column
      const f16* gA = Xc + (size_t)(row0 + r) * 1024 + k0 + kg;
      const f16* gB = Wc + (size_t)(col0 + r) * 1024 + k0 + kg;
      f16* lA = Ah + w * 1024 + j * 512;   // wave-uniform LDS base (+ lane*16 in HW)
      f16* lB = Bh + w * 1024 + j * 512;
      gload16(gA,       lA);               // Ah
      gload16(gA + 512, lA + 4096);        // Al
      gload16(gB,       lB);               // Bh
      gload16(gB + 512, lB + 4096);        // Bl
    }
    __syncthreads();   // drains vmcnt -> LDS tiles ready

    f16x8 ah[4], al[4];
    #pragma unroll
    for (int m = 0; m < 4; ++m) {
      const int rl = wr * 64 + m * 16 + cl;
      const int gs = g ^ ((rl >> 1) & 3);            // swizzled read column
      ah[m] = *(const f16x8*)(Ah + rl * 32 + gs * 8);
      al[m] = *(const f16x8*)(Al + rl * 32 + gs * 8);
    }
    #pragma unroll
    for (int n = 0; n < 4; ++n) {
      const int rl = wc * 64 + n * 16 + cl;
      const int gs = g ^ ((rl >> 1) & 3);
      f16x8 bh = *(const f16x8*)(Bh + rl * 32 + gs * 8);
      f16x8 bl = *(const f16x8*)(Bl + rl * 32 + gs * 8);
      #pragma unroll
      for (int m = 0; m < 4; ++m) {
        acc[m][n] = __builtin_amdgcn_mfma_f32_16x16x32_f16(ah[m], bh, acc[m][n], 0, 0, 0);
        acc[m][n] = __builtin_amdgcn_mfma_f32_16x16x32_f16(ah[m], bl, acc[m][n], 0, 0, 0);
        acc[m][n] = __builtin_amdgcn_mfma_f32_16x16x32_f16(al[m], bh, acc[m][n], 0, 0, 0);
      }
    }
    __syncthreads();   // all reads done before next stage overwrites
  }

  // ---- epilogue: score + argmin ----
  float wn[4];
  #pragma unroll
  for (int n = 0; n < 4; ++n) wn[n] = wnorm[col0 + wc * 64 + n * 16 + cl];

  unsigned long long* cmb = (unsigned long long*)smem;   // [128][2], 2 KB (post-loop reuse)

  #pragma unroll
  for (int m = 0; m < 4; ++m) {
    #pragma unroll
    for (int r = 0; r < 4; ++r) {
      unsigned long long pk = 0xFFFFFFFFFFFFFFFFULL;
      #pragma unroll
      for (int n = 0; n < 4; ++n) {
        float s = wn[n] - 2.0f * acc[m][n][r];
        unsigned int fb = __float_as_uint(s);
        fb ^= (fb & 0x80000000u) ? 0xFFFFFFFFu : 0x80000000u;   // order-preserving map
        unsigned long long k =
            ((unsigned long long)fb << 32) | (unsigned int)(col0 + wc * 64 + n * 16 + cl);
        pk = k < pk ? k : pk;
      }
      #pragma unroll
      for (int off = 1; off < 16; off <<= 1) {
        unsigned long long o = __shfl_xor(pk, off);
        pk = o < pk ? o : pk;
      }
      if (cl == 0) cmb[(wr * 64 + m * 16 + g * 4 + r) * 2 + wc] = pk;
    }
  }
  __syncthreads();
  if (tid < 128) {
    unsigned long long a = cmb[tid * 2], b = cmb[tid * 2 + 1];
    unsigned long long mn = a < b ? a : b;
    atomicMin(&pbest[(size_t)row0 + tid], mn);
  }
}

// ---------------- unpack pbest -> fidx ----------------
__global__ __launch_bounds__(256) void unpack_kernel(const unsigned long long* __restrict__ pbest,
                                                     int* __restrict__ fidx) {
  int i = blockIdx.x * 256 + threadIdx.x;
  if (i < M_TOK) fidx[i] = (int)(pbest[i] & 0xFFFFFFFFULL);
}

// ================= fp32 fallback path (R1, exact) =================
#define BM 128
#define BN 128
#define BK 16
#define LDPAD (BM + 4)
#define S_SPLIT 4
#define CODES_PER_SPLIT (N_EMB / S_SPLIT)
#define TILES_PER_SPLIT (CODES_PER_SPLIT / BN)

__global__ __launch_bounds__(256) void dist_argmin_kernel(
    const float* __restrict__ xs, const float* __restrict__ w,
    const float* __restrict__ wnorm,
    float* __restrict__ pval, int* __restrict__ pidx) {
  __shared__ float As[BK][LDPAD];
  __shared__ float Bs[BK][LDPAD];
  const int tid = threadIdx.x;
  const int tx = tid & 15, ty = tid >> 4;
  const int row0 = blockIdx.x * BM;
  const int s = blockIdx.y;
  const int code0 = s * CODES_PER_SPLIT;
  const int lm = tid >> 2, lk = (tid & 3) * 4;

  float rv[8]; int ri[8];
  #pragma unroll
  for (int i = 0; i < 8; i++) { rv[i] = 3.4e38f; ri[i] = 0x7fffffff; }

  for (int t = 0; t < TILES_PER_SPLIT; ++t) {
    const int col0 = code0 + t * BN;
    float acc[8][8];
    #pragma unroll
    for (int i = 0; i < 8; i++)
      #pragma unroll
      for (int j = 0; j < 8; j++) acc[i][j] = 0.f;

    for (int k0 = 0; k0 < D_K; k0 += BK) {
      float4 a0 = *(const float4*)(xs + (size_t)(row0 + lm)      * D_K + k0 + lk);
      float4 a1 = *(const float4*)(xs + (size_t)(row0 + lm + 64) * D_K + k0 + lk);
      float4 b0 = *(const float4*)(w  + (size_t)(col0 + lm)      * D_K + k0 + lk);
      float4 b1 = *(const float4*)(w  + (size_t)(col0 + lm + 64) * D_K + k0 + lk);
      __syncthreads();
      As[lk+0][lm]    = a0.x; As[lk+1][lm]    = a0.y; As[lk+2][lm]    = a0.z; As[lk+3][lm]    = a0.w;
      As[lk+0][lm+64] = a1.x; As[lk+1][lm+64] = a1.y; As[lk+2][lm+64] = a1.z; As[lk+3][lm+64] = a1.w;
      Bs[lk+0][lm]    = b0.x; Bs[lk+1][lm]    = b0.y; Bs[lk+2][lm]    = b0.z; Bs[lk+3][lm]    = b0.w;
      Bs[lk+0][lm+64] = b1.x; Bs[lk+1][lm+64] = b1.y; Bs[lk+2][lm+64] = b1.z; Bs[lk+3][lm+64] = b1.w;
      __syncthreads();
      #pragma unroll
      for (int kk = 0; kk < BK; kk++) {
        float a[8], b[8];
        *(float4*)&a[0] = *(const float4*)&As[kk][ty * 8];
        *(float4*)&a[4] = *(const float4*)&As[kk][ty * 8 + 4];
        *(float4*)&b[0] = *(const float4*)&Bs[kk][tx * 8];
        *(float4*)&b[4] = *(const float4*)&Bs[kk][tx * 8 + 4];
        #pragma unroll
        for (int i = 0; i < 8; i++)
          #pragma unroll
          for (int j = 0; j < 8; j++)
            acc[i][j] = fmaf(a[i], b[j], acc[i][j]);
      }
    }
    #pragma unroll
    for (int j = 0; j < 8; j++) {
      const int c = col0 + tx * 8 + j;
      const float wnv = wnorm[c];
      #pragma unroll
      for (int i = 0; i < 8; i++) {
        const float d = wnv - 2.f * acc[i][j];
        if (d < rv[i] || (d == rv[i] && c < ri[i])) { rv[i] = d; ri[i] = c; }
      }
    }
  }
  #pragma unroll
  for (int i = 0; i < 8; i++) {
    float v = rv[i]; int ix = ri[i];
    #pragma unroll
    for (int off = 1; off < 16; off <<= 1) {
      float ov = __shfl_xor(v, off);
      int   oi = __shfl_xor(ix, off);
      if (ov < v || (ov == v && oi < ix)) { v = ov; ix = oi; }
    }
    if (tx == 0) {
      const int row = row0 + ty * 8 + i;
      pval[(size_t)row * S_SPLIT + s] = v;
      pidx[(size_t)row * S_SPLIT + s] = ix;
    }
  }
}

__global__ __launch_bounds__(256) void reduce_idx_kernel(const float* __restrict__ pval,
                                                         const int* __restrict__ pidx,
                                                         int* __restrict__ fidx) {
  int i = blockIdx.x * 256 + threadIdx.x;
  if (i >= M_TOK) return;
  float bv = pval[(size_t)i * S_SPLIT];
  int   bi = pidx[(size_t)i * S_SPLIT];
  #pragma unroll
  for (int s = 1; s < S_SPLIT; s++) {
    float v = pval[(size_t)i * S_SPLIT + s];
    int  ix = pidx[(size_t)i * S_SPLIT + s];
    if (v < bv || (v == bv && ix < bi)) { bv = v; bi = ix; }
  }
  fidx[i] = bi;
}

// ---------------- gather: out = xs + (W[idx] - xs) ----------------
__global__ __launch_bounds__(256) void gather_kernel(const float* __restrict__ xs,
                                                     const float* __restrict__ w,
                                                     const int* __restrict__ fidx,
                                                     float* __restrict__ out) {
  int e = blockIdx.x * 256 + threadIdx.x;
  int row = e >> 7, off = e & 127;
  float4 xv = ((const float4*)(xs + (size_t)row * D_K))[off];
  float4 wv = ((const float4*)(w  + (size_t)fidx[row] * D_K))[off];
  float4 o;
  o.x = xv.x + (wv.x - xv.x);
  o.y = xv.y + (wv.y - xv.y);
  o.z = xv.z + (wv.z - xv.z);
  o.w = xv.w + (wv.w - xv.w);
  ((float4*)out)[e] = o;
}

extern "C" void kernel_launch(void* const* d_in, const int* in_sizes, int n_in,
                              void* d_out, int out_size, void* d_ws, size_t ws_size,
                              hipStream_t stream) {
  const float* xs = (const float*)d_in[0];
  const float* w  = (const float*)d_in[1];
  float* out = (float*)d_out;

  const size_t XC_B   = (size_t)M_TOK * 1024 * 2;   // 67108864
  const size_t WC_B   = (size_t)N_EMB * 1024 * 2;   // 16777216
  const size_t NEED   = XC_B + WC_B + N_EMB * 4 + M_TOK * 8 + M_TOK * 4 + 4096;

  if (ws_size >= NEED) {
    // ---- MFMA path ----
    f16* Xc = (f16*)d_ws;
    f16* Wc = (f16*)((char*)d_ws + XC_B);
    float* wnorm = (float*)((char*)d_ws + XC_B + WC_B);
    unsigned long long* pbest = (unsigned long long*)((char*)d_ws + XC_B + WC_B + N_EMB * 4);
    int* fidx = (int*)((char*)d_ws + XC_B + WC_B + N_EMB * 4 + (size_t)M_TOK * 8);

    convert_kernel<<<(M_TOK * 128) / 256, 256, 0, stream>>>(xs, Xc, M_TOK);
    convert_kernel<<<(N_EMB * 128) / 256, 256, 0, stream>>>(w,  Wc, N_EMB);
    wnorm_kernel<<<N_EMB / 4, 256, 0, stream>>>(w, wnorm);
    init_pbest_kernel<<<M_TOK / 256, 256, 0, stream>>>(pbest);
    dist_mfma_kernel<<<(M_TOK / 128) * (N_EMB / 128), 256, 0, stream>>>(Xc, Wc, wnorm, pbest);
    unpack_kernel<<<M_TOK / 256, 256, 0, stream>>>(pbest, fidx);
    gather_kernel<<<(M_TOK * (D_K / 4)) / 256, 256, 0, stream>>>(xs, w, fidx, out);
  } else {
    // ---- fp32 fallback (R1) ----
    float* wnorm = (float*)d_ws;
    float* pval  = wnorm + N_EMB;
    int*   pidx  = (int*)(pval + (size_t)M_TOK * S_SPLIT);
    int*   fidx  = pidx + (size_t)M_TOK * S_SPLIT;

    wnorm_kernel<<<N_EMB / 4, 256, 0, stream>>>(w, wnorm);
    dist_argmin_kernel<<<dim3(M_TOK / BM, S_SPLIT), 256, 0, stream>>>(xs, w, wnorm, pval, pidx);
    reduce_idx_kernel<<<M_TOK / 256, 256, 0, stream>>>(pval, pidx, fidx);
    gather_kernel<<<(M_TOK * (D_K / 4)) / 256, 256, 0, stream>>>(xs, w, fidx, out);
  }
}

// Round 3
// 496.007 us; speedup vs baseline: 6.6642x; 1.7741x over previous
//
#include <hip/hip_runtime.h>

// VQ codebook nearest-neighbor: xs [32768,512] f32, W [8192,512] f32
// out[i] = W[argmin_j ||xs_i - W_j||^2]
//
// R3: single-term f16 MFMA approximate pass (error <= ~0.06 in distance) +
//     per-block best-3 partials + exact fp32 fixup for near-tie tokens
//     (gap < 0.25; ~1.6% of tokens). 3x less MFMA work than R2.
// Fallback: exact fp32 path (R1) if ws too small.

#define M_TOK 32768
#define N_EMB 8192
#define D_K   512
#define FLAG_BAND 0.25f

typedef _Float16 f16;
typedef __attribute__((ext_vector_type(8))) _Float16 f16x8;
typedef __attribute__((ext_vector_type(4))) _Float16 f16x4;
typedef __attribute__((ext_vector_type(4))) float f32x4;
typedef unsigned long long u64;
typedef unsigned int u32;

__device__ __forceinline__ void gload16(const void* g, void* l) {
  __builtin_amdgcn_global_load_lds(
      (const __attribute__((address_space(1))) unsigned int*)g,
      (__attribute__((address_space(3))) unsigned int*)l, 16, 0, 0);
}

// order-preserving float<->u32 map (monotone: smaller float -> smaller uint)
__device__ __forceinline__ u32 map_f(float f) {
  u32 u = __float_as_uint(f);
  return u ^ ((u & 0x80000000u) ? 0xFFFFFFFFu : 0x80000000u);
}
__device__ __forceinline__ float unmap_f(u32 m) {
  return __uint_as_float((m & 0x80000000u) ? (m ^ 0x80000000u) : ~m);
}

// merge two sorted triples -> first 3 of union
__device__ __forceinline__ void merge3(u64& a1, u64& a2, u64& a3, u64 b1, u64 b2, u64 b3) {
  bool aw = a1 <= b1;
  u64 m1 = aw ? a1 : b1;
  u64 h2 = aw ? a2 : b2, h3 = aw ? a3 : b3;
  u64 l1 = aw ? b1 : a1, l2 = aw ? b2 : a2;
  u64 m2 = h2 <= l1 ? h2 : l1;
  u64 m3 = (h2 <= l1) ? (h3 <= l1 ? h3 : l1) : (h2 <= l2 ? h2 : l2);
  a1 = m1; a2 = m2; a3 = m3;
}

// ---------------- wnorm (+ zero the fixup counter) ----------------
__global__ __launch_bounds__(256) void wnorm_kernel(const float* __restrict__ w,
                                                    float* __restrict__ wnorm,
                                                    int* __restrict__ cnt) {
  if (blockIdx.x == 0 && threadIdx.x == 0) *cnt = 0;
  int row  = (blockIdx.x * 256 + threadIdx.x) >> 6;
  int lane = threadIdx.x & 63;
  if (row >= N_EMB) return;
  const float4* wr = (const float4*)(w + (size_t)row * D_K);
  float4 v0 = wr[lane * 2], v1 = wr[lane * 2 + 1];
  float s = v0.x*v0.x + v0.y*v0.y + v0.z*v0.z + v0.w*v0.w
          + v1.x*v1.x + v1.y*v1.y + v1.z*v1.z + v1.w*v1.w;
  #pragma unroll
  for (int off = 32; off; off >>= 1) s += __shfl_xor(s, off);
  if (lane == 0) wnorm[row] = s;
}

// ---------------- fp32 -> f16 (round-nearest hi part only) ----------------
__global__ __launch_bounds__(256) void convert_hi_kernel(const float* __restrict__ src,
                                                         f16* __restrict__ dst, int n4) {
  int e = blockIdx.x * 256 + threadIdx.x;
  if (e >= n4) return;
  float4 v = ((const float4*)src)[e];
  f16x4 h; h.x = (f16)v.x; h.y = (f16)v.y; h.z = (f16)v.z; h.w = (f16)v.w;
  *(f16x4*)(dst + (size_t)e * 4) = h;
}

// ---------------- approx distance (hi.hi) + per-block best-3 ----------------
// 128x128 tile, 4 waves (2x2), BK=32. LDS tiles XOR-swizzled (R2-proven, 0 conflicts).
__global__ __launch_bounds__(256, 2) void dist_mfma_kernel(
    const f16* __restrict__ Xh, const f16* __restrict__ Wh,
    const float* __restrict__ wnorm, uint4* __restrict__ partials) {
  __shared__ char smem[32768];
  f16* Ah = (f16*)smem;            // 8 KB (main loop)
  f16* Bh = (f16*)(smem + 8192);   // 8 KB
  float* sc = (float*)smem;        // 32 KB scores (epilogue reuse)

  int bid = (int)blockIdx.x;
  bid = (bid & 7) * 2048 + (bid >> 3);          // XCD swizzle (16384 % 8 == 0)
  const int rt = bid >> 6, ct = bid & 63;
  const int row0 = rt * 128, col0 = ct * 128;

  const int tid  = threadIdx.x;
  const int w    = tid >> 6, lane = tid & 63;
  const int wr   = w >> 1,   wc   = w & 1;
  const int g    = lane >> 4, cl  = lane & 15;

  f32x4 acc[4][4];
  #pragma unroll
  for (int i = 0; i < 4; i++)
    #pragma unroll
    for (int j = 0; j < 4; j++) acc[i][j] = (f32x4)(0.0f);

  for (int ks = 0; ks < 16; ++ks) {
    const int k0 = ks * 32;
    #pragma unroll
    for (int j = 0; j < 2; ++j) {
      const int c  = w * 128 + j * 64 + lane;
      const int r  = c >> 2;
      const int kg = ((c & 3) ^ ((r >> 1) & 3)) * 8;   // pre-swizzled source granule
      gload16(Xh + (size_t)(row0 + r) * 512 + k0 + kg, Ah + w * 1024 + j * 512);
      gload16(Wh + (size_t)(col0 + r) * 512 + k0 + kg, Bh + w * 1024 + j * 512);
    }
    __syncthreads();

    f16x8 ah[4];
    #pragma unroll
    for (int m = 0; m < 4; ++m) {
      const int rl = wr * 64 + m * 16 + cl;
      const int gs = g ^ ((rl >> 1) & 3);
      ah[m] = *(const f16x8*)(Ah + rl * 32 + gs * 8);
    }
    #pragma unroll
    for (int n = 0; n < 4; ++n) {
      const int rl = wc * 64 + n * 16 + cl;
      const int gs = g ^ ((rl >> 1) & 3);
      f16x8 bh = *(const f16x8*)(Bh + rl * 32 + gs * 8);
      #pragma unroll
      for (int m = 0; m < 4; ++m)
        acc[m][n] = __builtin_amdgcn_mfma_f32_16x16x32_f16(ah[m], bh, acc[m][n], 0, 0, 0);
    }
    __syncthreads();
  }

  // ---- epilogue: scores -> LDS (two 64-row passes) -> best-3 per row ----
  float wn[4];
  #pragma unroll
  for (int n = 0; n < 4; ++n) wn[n] = wnorm[col0 + wc * 64 + n * 16 + cl];

  for (int p = 0; p < 2; ++p) {
    __syncthreads();
    if (wr == p) {
      #pragma unroll
      for (int m = 0; m < 4; ++m)
        #pragma unroll
        for (int n = 0; n < 4; ++n)
          #pragma unroll
          for (int r = 0; r < 4; ++r)
            sc[(m * 16 + g * 4 + r) * 128 + wc * 64 + n * 16 + cl] =
                wn[n] - 2.0f * acc[m][n][r];
    }
    __syncthreads();

    const int row = tid >> 2, q = tid & 3;
    u64 c1 = ~0ULL, c2 = ~0ULL, c3 = ~0ULL;
    #pragma unroll 4
    for (int i = 0; i < 32; ++i) {
      const int col = q * 32 + ((i + row + q * 8) & 31);   // bank-rotated visit order
      float v = sc[row * 128 + col];
      u64 k = ((u64)map_f(v) << 32) | (u32)(col0 + col);
      if (k < c3) {
        if (k < c2) { c3 = c2; if (k < c1) { c2 = c1; c1 = k; } else c2 = k; }
        else c3 = k;
      }
    }
    #pragma unroll
    for (int off = 1; off < 4; off <<= 1) {
      u64 o1 = __shfl_xor(c1, off), o2 = __shfl_xor(c2, off), o3 = __shfl_xor(c3, off);
      merge3(c1, c2, c3, o1, o2, o3);
    }
    if (q == 0) {
      float v1 = unmap_f((u32)(c1 >> 32));
      float v2 = unmap_f((u32)(c2 >> 32));
      float v3 = unmap_f((u32)(c3 >> 32));
      u32 q2 = (u32)fminf(floorf((v2 - v1) * 1024.0f), 524287.0f);
      u32 q3 = (u32)fminf(floorf((v3 - v1) * 1024.0f), 524287.0f);
      uint4 e;
      e.x = (u32)(c1 & 0xFFFFFFFFu);
      e.y = (u32)(c1 >> 32);
      e.z = (q2 << 13) | ((u32)c2 & 0x1FFFu);
      e.w = (q3 << 13) | ((u32)c3 & 0x1FFFu);
      partials[(size_t)ct * M_TOK + row0 + p * 64 + row] = e;
    }
  }
}

// ---------------- global best-2 + flag near-ties ----------------
__global__ __launch_bounds__(256) void reduce_kernel(
    const uint4* __restrict__ partials, u64* __restrict__ bestkey,
    int* __restrict__ fidx, int* __restrict__ flaglist, int* __restrict__ cnt) {
  int t = blockIdx.x * 256 + threadIdx.x;
  if (t >= M_TOK) return;
  u64 b1 = ~0ULL, b2 = ~0ULL;
  for (int ct = 0; ct < 64; ++ct) {
    uint4 e = partials[(size_t)ct * M_TOK + t];
    u64 k1 = ((u64)e.y << 32) | e.x;
    float v1 = unmap_f(e.y);
    float v2 = v1 + (float)(e.z >> 13) * (1.0f / 1024.0f);
    u64 k2 = ((u64)map_f(v2) << 32) | (e.z & 0x1FFFu);
    u64 lo = b1 < k1 ? b1 : k1;
    u64 hi = b1 < k1 ? k1 : b1;
    u64 mk = b2 < k2 ? b2 : k2;
    b1 = lo; b2 = hi < mk ? hi : mk;
  }
  bestkey[t] = b1;
  fidx[t] = (int)(b1 & 0xFFFFFFFFu);
  float gap = unmap_f((u32)(b2 >> 32)) - unmap_f((u32)(b1 >> 32));
  if (gap < FLAG_BAND) flaglist[atomicAdd(cnt, 1)] = t;
}

// ---------------- exact fp32 re-rank for flagged tokens ----------------
__global__ __launch_bounds__(256) void fixup_kernel(
    const float* __restrict__ xs, const float* __restrict__ w,
    const float* __restrict__ wnorm, const uint4* __restrict__ partials,
    const u64* __restrict__ bestkey, const int* __restrict__ flaglist,
    const int* __restrict__ cnt, int* __restrict__ fidx) {
  __shared__ int s_cand[256];
  __shared__ int s_n;
  __shared__ u64 s_best;
  const int n_flag = *cnt;
  for (int ii = blockIdx.x; ii < n_flag; ii += gridDim.x) {
    const int t = flaglist[ii];
    if (threadIdx.x == 0) { s_n = 0; s_best = ~0ULL; }
    __syncthreads();
    const float v1 = unmap_f((u32)(bestkey[t] >> 32));
    if (threadIdx.x < 64) {
      uint4 e = partials[(size_t)threadIdx.x * M_TOK + t];
      float a1 = unmap_f(e.y);
      if (a1 <= v1 + FLAG_BAND) s_cand[atomicAdd(&s_n, 1)] = (int)(e.x & 0x1FFFu);
      float a2 = a1 + (float)(e.z >> 13) * (1.0f / 1024.0f);
      if (a2 <= v1 + FLAG_BAND) s_cand[atomicAdd(&s_n, 1)] = (int)(e.z & 0x1FFFu);
      float a3 = a1 + (float)(e.w >> 13) * (1.0f / 1024.0f);
      if (a3 <= v1 + FLAG_BAND) s_cand[atomicAdd(&s_n, 1)] = (int)(e.w & 0x1FFFu);
    }
    __syncthreads();
    const int n = s_n;
    const int wid = threadIdx.x >> 6, lane = threadIdx.x & 63;
    for (int c = wid; c < n; c += 4) {
      const int j = s_cand[c];
      const float4* xr = (const float4*)(xs + (size_t)t * D_K);
      const float4* wr = (const float4*)(w + (size_t)j * D_K);
      float4 a0 = xr[lane * 2], a1 = xr[lane * 2 + 1];
      float4 b0 = wr[lane * 2], b1 = wr[lane * 2 + 1];
      float s = a0.x*b0.x + a0.y*b0.y + a0.z*b0.z + a0.w*b0.w
              + a1.x*b1.x + a1.y*b1.y + a1.z*b1.z + a1.w*b1.w;
      #pragma unroll
      for (int off = 32; off; off >>= 1) s += __shfl_xor(s, off);
      if (lane == 0) {
        float score = wnorm[j] - 2.0f * s;
        u64 k = ((u64)map_f(score) << 32) | (u32)j;
        atomicMin(&s_best, k);
      }
    }
    __syncthreads();
    if (threadIdx.x == 0) fidx[t] = (int)(s_best & 0xFFFFFFFFu);
    __syncthreads();
  }
}

// ---------------- gather: out = xs + (W[idx] - xs) ----------------
__global__ __launch_bounds__(256) void gather_kernel(const float* __restrict__ xs,
                                                     const float* __restrict__ w,
                                                     const int* __restrict__ fidx,
                                                     float* __restrict__ out) {
  int e = blockIdx.x * 256 + threadIdx.x;
  int row = e >> 7, off = e & 127;
  float4 xv = ((const float4*)(xs + (size_t)row * D_K))[off];
  float4 wv = ((const float4*)(w  + (size_t)fidx[row] * D_K))[off];
  float4 o;
  o.x = xv.x + (wv.x - xv.x);
  o.y = xv.y + (wv.y - xv.y);
  o.z = xv.z + (wv.z - xv.z);
  o.w = xv.w + (wv.w - xv.w);
  ((float4*)out)[e] = o;
}

// ================= fp32 fallback path (R1, exact) =================
#define BM 128
#define BN 128
#define BK 16
#define LDPAD (BM + 4)
#define S_SPLIT 4
#define CODES_PER_SPLIT (N_EMB / S_SPLIT)
#define TILES_PER_SPLIT (CODES_PER_SPLIT / BN)

__global__ __launch_bounds__(256) void dist_argmin_kernel(
    const float* __restrict__ xs, const float* __restrict__ w,
    const float* __restrict__ wnorm,
    float* __restrict__ pval, int* __restrict__ pidx) {
  __shared__ float As[BK][LDPAD];
  __shared__ float Bs[BK][LDPAD];
  const int tid = threadIdx.x;
  const int tx = tid & 15, ty = tid >> 4;
  const int row0 = blockIdx.x * BM;
  const int s = blockIdx.y;
  const int code0 = s * CODES_PER_SPLIT;
  const int lm = tid >> 2, lk = (tid & 3) * 4;
  float rv[8]; int ri[8];
  #pragma unroll
  for (int i = 0; i < 8; i++) { rv[i] = 3.4e38f; ri[i] = 0x7fffffff; }
  for (int t = 0; t < TILES_PER_SPLIT; ++t) {
    const int col0 = code0 + t * BN;
    float acc[8][8];
    #pragma unroll
    for (int i = 0; i < 8; i++)
      #pragma unroll
      for (int j = 0; j < 8; j++) acc[i][j] = 0.f;
    for (int k0 = 0; k0 < D_K; k0 += BK) {
      float4 a0 = *(const float4*)(xs + (size_t)(row0 + lm)      * D_K + k0 + lk);
      float4 a1 = *(const float4*)(xs + (size_t)(row0 + lm + 64) * D_K + k0 + lk);
      float4 b0 = *(const float4*)(w  + (size_t)(col0 + lm)      * D_K + k0 + lk);
      float4 b1 = *(const float4*)(w  + (size_t)(col0 + lm + 64) * D_K + k0 + lk);
      __syncthreads();
      As[lk+0][lm]    = a0.x; As[lk+1][lm]    = a0.y; As[lk+2][lm]    = a0.z; As[lk+3][lm]    = a0.w;
      As[lk+0][lm+64] = a1.x; As[lk+1][lm+64] = a1.y; As[lk+2][lm+64] = a1.z; As[lk+3][lm+64] = a1.w;
      Bs[lk+0][lm]    = b0.x; Bs[lk+1][lm]    = b0.y; Bs[lk+2][lm]    = b0.z; Bs[lk+3][lm]    = b0.w;
      Bs[lk+0][lm+64] = b1.x; Bs[lk+1][lm+64] = b1.y; Bs[lk+2][lm+64] = b1.z; Bs[lk+3][lm+64] = b1.w;
      __syncthreads();
      #pragma unroll
      for (int kk = 0; kk < BK; kk++) {
        float a[8], b[8];
        *(float4*)&a[0] = *(const float4*)&As[kk][ty * 8];
        *(float4*)&a[4] = *(const float4*)&As[kk][ty * 8 + 4];
        *(float4*)&b[0] = *(const float4*)&Bs[kk][tx * 8];
        *(float4*)&b[4] = *(const float4*)&Bs[kk][tx * 8 + 4];
        #pragma unroll
        for (int i = 0; i < 8; i++)
          #pragma unroll
          for (int j = 0; j < 8; j++)
            acc[i][j] = fmaf(a[i], b[j], acc[i][j]);
      }
    }
    #pragma unroll
    for (int j = 0; j < 8; j++) {
      const int c = col0 + tx * 8 + j;
      const float wnv = wnorm[c];
      #pragma unroll
      for (int i = 0; i < 8; i++) {
        const float d = wnv - 2.f * acc[i][j];
        if (d < rv[i] || (d == rv[i] && c < ri[i])) { rv[i] = d; ri[i] = c; }
      }
    }
  }
  #pragma unroll
  for (int i = 0; i < 8; i++) {
    float v = rv[i]; int ix = ri[i];
    #pragma unroll
    for (int off = 1; off < 16; off <<= 1) {
      float ov = __shfl_xor(v, off);
      int   oi = __shfl_xor(ix, off);
      if (ov < v || (ov == v && oi < ix)) { v = ov; ix = oi; }
    }
    if (tx == 0) {
      const int row = row0 + ty * 8 + i;
      pval[(size_t)row * S_SPLIT + s] = v;
      pidx[(size_t)row * S_SPLIT + s] = ix;
    }
  }
}

__global__ __launch_bounds__(256) void reduce_idx_kernel(const float* __restrict__ pval,
                                                         const int* __restrict__ pidx,
                                                         int* __restrict__ fidx) {
  int i = blockIdx.x * 256 + threadIdx.x;
  if (i >= M_TOK) return;
  float bv = pval[(size_t)i * S_SPLIT];
  int   bi = pidx[(size_t)i * S_SPLIT];
  #pragma unroll
  for (int s = 1; s < S_SPLIT; s++) {
    float v = pval[(size_t)i * S_SPLIT + s];
    int  ix = pidx[(size_t)i * S_SPLIT + s];
    if (v < bv || (v == bv && ix < bi)) { bv = v; bi = ix; }
  }
  fidx[i] = bi;
}

extern "C" void kernel_launch(void* const* d_in, const int* in_sizes, int n_in,
                              void* d_out, int out_size, void* d_ws, size_t ws_size,
                              hipStream_t stream) {
  const float* xs = (const float*)d_in[0];
  const float* w  = (const float*)d_in[1];
  float* out = (float*)d_out;

  // ws layout (~76 MB)
  const size_t XH_B   = (size_t)M_TOK * D_K * 2;          // 33,554,432
  const size_t WH_B   = (size_t)N_EMB * D_K * 2;          //  8,388,608
  const size_t WN_B   = (size_t)N_EMB * 4;                //     32,768
  const size_t PART_B = (size_t)64 * M_TOK * 16;          // 33,554,432
  const size_t BK_B   = (size_t)M_TOK * 8;                //    262,144
  const size_t FI_B   = (size_t)M_TOK * 4;                //    131,072
  const size_t FL_B   = (size_t)M_TOK * 4;                //    131,072
  const size_t NEED   = XH_B + WH_B + WN_B + PART_B + BK_B + FI_B + FL_B + 128;

  if (ws_size >= NEED) {
    char* p = (char*)d_ws;
    f16*   Xh       = (f16*)p;                 p += XH_B;
    f16*   Wh       = (f16*)p;                 p += WH_B;
    float* wnorm    = (float*)p;               p += WN_B;
    uint4* partials = (uint4*)p;               p += PART_B;
    u64*   bestkey  = (u64*)p;                 p += BK_B;
    int*   fidx     = (int*)p;                 p += FI_B;
    int*   flaglist = (int*)p;                 p += FL_B;
    int*   cnt      = (int*)p;

    convert_hi_kernel<<<(M_TOK * 128) / 256, 256, 0, stream>>>(xs, Xh, M_TOK * 128);
    convert_hi_kernel<<<(N_EMB * 128) / 256, 256, 0, stream>>>(w,  Wh, N_EMB * 128);
    wnorm_kernel<<<N_EMB / 4, 256, 0, stream>>>(w, wnorm, cnt);
    dist_mfma_kernel<<<(M_TOK / 128) * (N_EMB / 128), 256, 0, stream>>>(Xh, Wh, wnorm, partials);
    reduce_kernel<<<M_TOK / 256, 256, 0, stream>>>(partials, bestkey, fidx, flaglist, cnt);
    fixup_kernel<<<256, 256, 0, stream>>>(xs, w, wnorm, partials, bestkey, flaglist, cnt, fidx);
    gather_kernel<<<(M_TOK * (D_K / 4)) / 256, 256, 0, stream>>>(xs, w, fidx, out);
  } else {
    float* wnorm = (float*)d_ws;
    float* pval  = wnorm + N_EMB;
    int*   pidx  = (int*)(pval + (size_t)M_TOK * S_SPLIT);
    int*   fidx  = pidx + (size_t)M_TOK * S_SPLIT;
    int*   cnt   = fidx + M_TOK;
    wnorm_kernel<<<N_EMB / 4, 256, 0, stream>>>(w, wnorm, cnt);
    dist_argmin_kernel<<<dim3(M_TOK / BM, S_SPLIT), 256, 0, stream>>>(xs, w, wnorm, pval, pidx);
    reduce_idx_kernel<<<M_TOK / 256, 256, 0, stream>>>(pval, pidx, fidx);
    gather_kernel<<<(M_TOK * (D_K / 4)) / 256, 256, 0, stream>>>(xs, w, fidx, out);
  }
}

// Round 4
// 494.286 us; speedup vs baseline: 6.6874x; 1.0035x over previous
//
#include <hip/hip_runtime.h>

// VQ codebook nearest-neighbor: xs [32768,512] f32, W [8192,512] f32
// out[i] = W[argmin_j ||xs_i - W_j||^2]
//
// R4: f16 MFMA approx pass with lean u32-key epilogue (positive-offset score,
//     quantized bits + 7-bit local col, min/max best-2) + 2-phase double-buffered
//     main loop (BK=64, 1 barrier/K-tile). Exact fp32 fixup for near-ties.

#define M_TOK 32768
#define N_EMB 8192
#define D_K   512
#define WOFF  2048.0f
#define QMASK 0xFFFFFF80u
#define BAND  0.375f

typedef _Float16 f16;
typedef __attribute__((ext_vector_type(8))) _Float16 f16x8;
typedef __attribute__((ext_vector_type(4))) _Float16 f16x4;
typedef __attribute__((ext_vector_type(4))) float f32x4;
typedef unsigned long long u64;
typedef unsigned int u32;

__device__ __forceinline__ void gload16(const void* g, void* l) {
  __builtin_amdgcn_global_load_lds(
      (const __attribute__((address_space(1))) unsigned int*)g,
      (__attribute__((address_space(3))) unsigned int*)l, 16, 0, 0);
}

__device__ __forceinline__ u32 map_f(float f) {   // exact order-preserving (fixup only)
  u32 u = __float_as_uint(f);
  return u ^ ((u & 0x80000000u) ? 0xFFFFFFFFu : 0x80000000u);
}
__device__ __forceinline__ float qval(u32 key) {  // quantized approx value
  return __uint_as_float(key & QMASK) - WOFF;
}

// ---------------- wnorm (exact, no offset) + zero counter ----------------
__global__ __launch_bounds__(256) void wnorm_kernel(const float* __restrict__ w,
                                                    float* __restrict__ wnorm,
                                                    int* __restrict__ cnt) {
  if (blockIdx.x == 0 && threadIdx.x == 0) *cnt = 0;
  int row  = (blockIdx.x * 256 + threadIdx.x) >> 6;
  int lane = threadIdx.x & 63;
  if (row >= N_EMB) return;
  const float4* wr = (const float4*)(w + (size_t)row * D_K);
  float4 v0 = wr[lane * 2], v1 = wr[lane * 2 + 1];
  float s = v0.x*v0.x + v0.y*v0.y + v0.z*v0.z + v0.w*v0.w
          + v1.x*v1.x + v1.y*v1.y + v1.z*v1.z + v1.w*v1.w;
  #pragma unroll
  for (int off = 32; off; off >>= 1) s += __shfl_xor(s, off);
  if (lane == 0) wnorm[row] = s;
}

// ---------------- fp32 -> f16 (round-nearest) ----------------
__global__ __launch_bounds__(256) void convert_hi_kernel(const float* __restrict__ src,
                                                         f16* __restrict__ dst, int n4) {
  int e = blockIdx.x * 256 + threadIdx.x;
  if (e >= n4) return;
  float4 v = ((const float4*)src)[e];
  f16x4 h; h.x = (f16)v.x; h.y = (f16)v.y; h.z = (f16)v.z; h.w = (f16)v.w;
  *(f16x4*)(dst + (size_t)e * 4) = h;
}

// ---------------- approx distance + per-block best-2 (u32 keys) ----------------
// 128x128 tile, 4 waves (2x2), BK=64, double-buffered LDS (2x32KB), XOR swizzle.
__global__ __launch_bounds__(256, 2) void dist_mfma_kernel(
    const f16* __restrict__ Xh, const f16* __restrict__ Wh,
    const float* __restrict__ wnorm, uint2* __restrict__ partials) {
  __shared__ char smem[65536];   // buf b: A at b*32768, B at b*32768+16384

  int bid = (int)blockIdx.x;
  bid = (bid & 7) * 2048 + (bid >> 3);          // XCD swizzle (16384 % 8 == 0)
  const int rt = bid >> 6, ct = bid & 63;
  const int row0 = rt * 128, col0 = ct * 128;

  const int tid  = threadIdx.x;
  const int w    = tid >> 6, lane = tid & 63;
  const int wr   = w >> 1,   wc   = w & 1;
  const int g    = lane >> 4, cl  = lane & 15;

  // staging descriptors: chunk c = w*256 + j*64 + lane  (16B chunks, 1024/tile)
  size_t offA[4], offB[4];
  #pragma unroll
  for (int j = 0; j < 4; ++j) {
    const int c    = w * 256 + j * 64 + lane;
    const int r    = c >> 3;
    const int gsrc = (c & 7) ^ (r & 7);
    offA[j] = (size_t)(row0 + r) * 1024 + gsrc * 16;   // bytes (X row = 1024 B)
    offB[j] = (size_t)(col0 + r) * 1024 + gsrc * 16;
  }
  const char* Xb = (const char*)Xh;
  const char* Wb = (const char*)Wh;

  f32x4 acc[4][4];
  #pragma unroll
  for (int i = 0; i < 4; i++)
    #pragma unroll
    for (int j = 0; j < 4; j++) acc[i][j] = (f32x4)(0.0f);

  #define STAGE(buf, t)                                                        \
    {                                                                          \
      const int k0b = (t) * 128;                                               \
      char* la = smem + (buf) * 32768 + w * 4096;                              \
      char* lb = la + 16384;                                                   \
      _Pragma("unroll")                                                        \
      for (int j = 0; j < 4; ++j) {                                            \
        gload16(Xb + offA[j] + k0b, la + j * 1024);                            \
        gload16(Wb + offB[j] + k0b, lb + j * 1024);                            \
      }                                                                        \
    }

  STAGE(0, 0);
  __syncthreads();

  for (int t = 0; t < 8; ++t) {
    if (t < 7) STAGE((t + 1) & 1, t + 1);

    const f16* pA = (const f16*)(smem + (t & 1) * 32768);
    const f16* pB = (const f16*)(smem + (t & 1) * 32768 + 16384);
    #pragma unroll
    for (int kk = 0; kk < 2; ++kk) {
      f16x8 ah[4], bh[4];
      #pragma unroll
      for (int m = 0; m < 4; ++m) {
        const int rl = wr * 64 + m * 16 + cl;
        const int sl = (kk * 4 + g) ^ (rl & 7);
        ah[m] = *(const f16x8*)(pA + rl * 64 + sl * 8);
      }
      #pragma unroll
      for (int n = 0; n < 4; ++n) {
        const int rl = wc * 64 + n * 16 + cl;
        const int sl = (kk * 4 + g) ^ (rl & 7);
        bh[n] = *(const f16x8*)(pB + rl * 64 + sl * 8);
      }
      #pragma unroll
      for (int n = 0; n < 4; ++n)
        #pragma unroll
        for (int m = 0; m < 4; ++m)
          acc[m][n] = __builtin_amdgcn_mfma_f32_16x16x32_f16(ah[m], bh[n], acc[m][n], 0, 0, 0);
    }
    __syncthreads();   // drains vmcnt(0): next buffer staged; lgkm done
  }
  #undef STAGE

  // ---- epilogue: u32 keys, per-row best-2 ----
  float wnp[4];
  u32 colb[4];
  #pragma unroll
  for (int n = 0; n < 4; ++n) {
    wnp[n]  = wnorm[col0 + wc * 64 + n * 16 + cl] + WOFF;   // positive-offset score
    colb[n] = (u32)(wc * 64 + n * 16 + cl);                 // local col, 7 bits
  }

  uint2* cmb = (uint2*)smem;   // [128][2] (reuse buf0-A region; post-barrier)

  #pragma unroll
  for (int m = 0; m < 4; ++m) {
    #pragma unroll
    for (int r = 0; r < 4; ++r) {
      u32 k0, k1, k2, k3;
      {
        float s0 = fmaf(-2.0f, acc[m][0][r], wnp[0]);
        float s1 = fmaf(-2.0f, acc[m][1][r], wnp[1]);
        float s2 = fmaf(-2.0f, acc[m][2][r], wnp[2]);
        float s3 = fmaf(-2.0f, acc[m][3][r], wnp[3]);
        k0 = (__float_as_uint(s0) & QMASK) | colb[0];
        k1 = (__float_as_uint(s1) & QMASK) | colb[1];
        k2 = (__float_as_uint(s2) & QMASK) | colb[2];
        k3 = (__float_as_uint(s3) & QMASK) | colb[3];
      }
      u32 a = min(k0, k1), b = max(k0, k1);
      u32 c = min(k2, k3), d = max(k2, k3);
      u32 c1 = min(a, c);
      u32 c2 = min(max(a, c), min(b, d));
      #pragma unroll
      for (int off = 1; off < 16; off <<= 1) {
        u32 o1 = __shfl_xor(c1, off), o2 = __shfl_xor(c2, off);
        u32 n1 = min(c1, o1);
        c2 = min(min(c2, o2), max(c1, o1));
        c1 = n1;
      }
      if (cl == 0) cmb[(wr * 64 + m * 16 + g * 4 + r) * 2 + wc] = make_uint2(c1, c2);
    }
  }
  __syncthreads();
  if (tid < 128) {
    uint2 A = cmb[tid * 2], B = cmb[tid * 2 + 1];
    u32 c1 = min(A.x, B.x);
    u32 c2 = min(max(A.x, B.x), min(A.y, B.y));
    partials[(size_t)ct * M_TOK + row0 + tid] = make_uint2(c1, c2);
  }
}

// ---------------- global best-2 + flag near-ties ----------------
__global__ __launch_bounds__(256) void reduce_kernel(
    const uint2* __restrict__ partials, u32* __restrict__ bestkey,
    int* __restrict__ fidx, int* __restrict__ flaglist, int* __restrict__ cnt) {
  int t = blockIdx.x * 256 + threadIdx.x;
  if (t >= M_TOK) return;
  u32 b1 = 0xFFFFFFFFu, b2 = 0xFFFFFFFFu;
  int bidx = 0;
  for (int ct = 0; ct < 64; ++ct) {
    uint2 e = partials[(size_t)ct * M_TOK + t];
    if (e.x < b1) {
      b2 = min(b1, min(b2, e.y));
      b1 = e.x;
      bidx = ct * 128 + (int)(e.x & 127u);
    } else {
      b2 = min(b2, e.x);
    }
  }
  bestkey[t] = b1;
  fidx[t] = bidx;
  if (qval(b2) - qval(b1) < BAND) flaglist[atomicAdd(cnt, 1)] = t;
}

// ---------------- exact fp32 re-rank for flagged tokens ----------------
__global__ __launch_bounds__(256) void fixup_kernel(
    const float* __restrict__ xs, const float* __restrict__ w,
    const float* __restrict__ wnorm, const uint2* __restrict__ partials,
    const u32* __restrict__ bestkey, const int* __restrict__ flaglist,
    const int* __restrict__ cnt, int* __restrict__ fidx) {
  __shared__ int s_cand[8320];
  __shared__ int s_n;
  __shared__ u64 s_best;
  const int n_flag = *cnt;
  for (int ii = blockIdx.x; ii < n_flag; ii += gridDim.x) {
    const int t = flaglist[ii];
    if (threadIdx.x == 0) { s_n = 0; s_best = ~0ULL; }
    __syncthreads();
    const float thr = qval(bestkey[t]) + BAND;
    if (threadIdx.x < 64) {
      uint2 e = partials[(size_t)threadIdx.x * M_TOK + t];
      if (qval(e.x) <= thr)
        s_cand[atomicAdd(&s_n, 1)] = (int)threadIdx.x * 128 + (int)(e.x & 127u);
      if (qval(e.y) <= thr) {                // possible hidden 3rd: scan whole block
        int base = atomicAdd(&s_n, 128);
        for (int c = 0; c < 128; ++c) s_cand[base + c] = (int)threadIdx.x * 128 + c;
      }
    }
    __syncthreads();
    const int n = s_n;
    const int wid = threadIdx.x >> 6, lane = threadIdx.x & 63;
    for (int c = wid; c < n; c += 4) {
      const int j = s_cand[c];
      const float4* xr = (const float4*)(xs + (size_t)t * D_K);
      const float4* wr = (const float4*)(w + (size_t)j * D_K);
      float4 a0 = xr[lane * 2], a1 = xr[lane * 2 + 1];
      float4 b0 = wr[lane * 2], b1 = wr[lane * 2 + 1];
      float s = a0.x*b0.x + a0.y*b0.y + a0.z*b0.z + a0.w*b0.w
              + a1.x*b1.x + a1.y*b1.y + a1.z*b1.z + a1.w*b1.w;
      #pragma unroll
      for (int off = 32; off; off >>= 1) s += __shfl_xor(s, off);
      if (lane == 0) {
        float score = wnorm[j] - 2.0f * s;
        u64 k = ((u64)map_f(score) << 32) | (u32)j;
        atomicMin(&s_best, k);
      }
    }
    __syncthreads();
    if (threadIdx.x == 0) fidx[t] = (int)(s_best & 0xFFFFFFFFULL);
    __syncthreads();
  }
}

// ---------------- gather: out = xs + (W[idx] - xs) ----------------
__global__ __launch_bounds__(256) void gather_kernel(const float* __restrict__ xs,
                                                     const float* __restrict__ w,
                                                     const int* __restrict__ fidx,
                                                     float* __restrict__ out) {
  int e = blockIdx.x * 256 + threadIdx.x;
  int row = e >> 7, off = e & 127;
  float4 xv = ((const float4*)(xs + (size_t)row * D_K))[off];
  float4 wv = ((const float4*)(w  + (size_t)fidx[row] * D_K))[off];
  float4 o;
  o.x = xv.x + (wv.x - xv.x);
  o.y = xv.y + (wv.y - xv.y);
  o.z = xv.z + (wv.z - xv.z);
  o.w = xv.w + (wv.w - xv.w);
  ((float4*)out)[e] = o;
}

// ================= fp32 fallback path (R1, exact) =================
#define BM 128
#define BN 128
#define BK 16
#define LDPAD (BM + 4)
#define S_SPLIT 4
#define CODES_PER_SPLIT (N_EMB / S_SPLIT)
#define TILES_PER_SPLIT (CODES_PER_SPLIT / BN)

__global__ __launch_bounds__(256) void dist_argmin_kernel(
    const float* __restrict__ xs, const float* __restrict__ w,
    const float* __restrict__ wnorm,
    float* __restrict__ pval, int* __restrict__ pidx) {
  __shared__ float As[BK][LDPAD];
  __shared__ float Bs[BK][LDPAD];
  const int tid = threadIdx.x;
  const int tx = tid & 15, ty = tid >> 4;
  const int row0 = blockIdx.x * BM;
  const int s = blockIdx.y;
  const int code0 = s * CODES_PER_SPLIT;
  const int lm = tid >> 2, lk = (tid & 3) * 4;
  float rv[8]; int ri[8];
  #pragma unroll
  for (int i = 0; i < 8; i++) { rv[i] = 3.4e38f; ri[i] = 0x7fffffff; }
  for (int t = 0; t < TILES_PER_SPLIT; ++t) {
    const int col0 = code0 + t * BN;
    float acc[8][8];
    #pragma unroll
    for (int i = 0; i < 8; i++)
      #pragma unroll
      for (int j = 0; j < 8; j++) acc[i][j] = 0.f;
    for (int k0 = 0; k0 < D_K; k0 += BK) {
      float4 a0 = *(const float4*)(xs + (size_t)(row0 + lm)      * D_K + k0 + lk);
      float4 a1 = *(const float4*)(xs + (size_t)(row0 + lm + 64) * D_K + k0 + lk);
      float4 b0 = *(const float4*)(w  + (size_t)(col0 + lm)      * D_K + k0 + lk);
      float4 b1 = *(const float4*)(w  + (size_t)(col0 + lm + 64) * D_K + k0 + lk);
      __syncthreads();
      As[lk+0][lm]    = a0.x; As[lk+1][lm]    = a0.y; As[lk+2][lm]    = a0.z; As[lk+3][lm]    = a0.w;
      As[lk+0][lm+64] = a1.x; As[lk+1][lm+64] = a1.y; As[lk+2][lm+64] = a1.z; As[lk+3][lm+64] = a1.w;
      Bs[lk+0][lm]    = b0.x; Bs[lk+1][lm]    = b0.y; Bs[lk+2][lm]    = b0.z; Bs[lk+3][lm]    = b0.w;
      Bs[lk+0][lm+64] = b1.x; Bs[lk+1][lm+64] = b1.y; Bs[lk+2][lm+64] = b1.z; Bs[lk+3][lm+64] = b1.w;
      __syncthreads();
      #pragma unroll
      for (int kk = 0; kk < BK; kk++) {
        float a[8], b[8];
        *(float4*)&a[0] = *(const float4*)&As[kk][ty * 8];
        *(float4*)&a[4] = *(const float4*)&As[kk][ty * 8 + 4];
        *(float4*)&b[0] = *(const float4*)&Bs[kk][tx * 8];
        *(float4*)&b[4] = *(const float4*)&Bs[kk][tx * 8 + 4];
        #pragma unroll
        for (int i = 0; i < 8; i++)
          #pragma unroll
          for (int j = 0; j < 8; j++)
            acc[i][j] = fmaf(a[i], b[j], acc[i][j]);
      }
    }
    #pragma unroll
    for (int j = 0; j < 8; j++) {
      const int c = col0 + tx * 8 + j;
      const float wnv = wnorm[c];
      #pragma unroll
      for (int i = 0; i < 8; i++) {
        const float d = wnv - 2.f * acc[i][j];
        if (d < rv[i] || (d == rv[i] && c < ri[i])) { rv[i] = d; ri[i] = c; }
      }
    }
  }
  #pragma unroll
  for (int i = 0; i < 8; i++) {
    float v = rv[i]; int ix = ri[i];
    #pragma unroll
    for (int off = 1; off < 16; off <<= 1) {
      float ov = __shfl_xor(v, off);
      int   oi = __shfl_xor(ix, off);
      if (ov < v || (ov == v && oi < ix)) { v = ov; ix = oi; }
    }
    if (tx == 0) {
      const int row = row0 + ty * 8 + i;
      pval[(size_t)row * S_SPLIT + s] = v;
      pidx[(size_t)row * S_SPLIT + s] = ix;
    }
  }
}

__global__ __launch_bounds__(256) void reduce_idx_kernel(const float* __restrict__ pval,
                                                         const int* __restrict__ pidx,
                                                         int* __restrict__ fidx) {
  int i = blockIdx.x * 256 + threadIdx.x;
  if (i >= M_TOK) return;
  float bv = pval[(size_t)i * S_SPLIT];
  int   bi = pidx[(size_t)i * S_SPLIT];
  #pragma unroll
  for (int s = 1; s < S_SPLIT; s++) {
    float v = pval[(size_t)i * S_SPLIT + s];
    int  ix = pidx[(size_t)i * S_SPLIT + s];
    if (v < bv || (v == bv && ix < bi)) { bv = v; bi = ix; }
  }
  fidx[i] = bi;
}

extern "C" void kernel_launch(void* const* d_in, const int* in_sizes, int n_in,
                              void* d_out, int out_size, void* d_ws, size_t ws_size,
                              hipStream_t stream) {
  const float* xs = (const float*)d_in[0];
  const float* w  = (const float*)d_in[1];
  float* out = (float*)d_out;

  // ws layout (~57 MB)
  const size_t XH_B   = (size_t)M_TOK * D_K * 2;          // 33,554,432
  const size_t WH_B   = (size_t)N_EMB * D_K * 2;          //  8,388,608
  const size_t WN_B   = (size_t)N_EMB * 4;                //     32,768
  const size_t PART_B = (size_t)64 * M_TOK * 8;           // 16,777,216
  const size_t BK_B   = (size_t)M_TOK * 4;                //    131,072
  const size_t FI_B   = (size_t)M_TOK * 4;                //    131,072
  const size_t FL_B   = (size_t)M_TOK * 4;                //    131,072
  const size_t NEED   = XH_B + WH_B + WN_B + PART_B + BK_B + FI_B + FL_B + 128;

  if (ws_size >= NEED) {
    char* p = (char*)d_ws;
    f16*   Xh       = (f16*)p;                 p += XH_B;
    f16*   Wh       = (f16*)p;                 p += WH_B;
    float* wnorm    = (float*)p;               p += WN_B;
    uint2* partials = (uint2*)p;               p += PART_B;
    u32*   bestkey  = (u32*)p;                 p += BK_B;
    int*   fidx     = (int*)p;                 p += FI_B;
    int*   flaglist = (int*)p;                 p += FL_B;
    int*   cnt      = (int*)p;

    convert_hi_kernel<<<(M_TOK * 128) / 256, 256, 0, stream>>>(xs, Xh, M_TOK * 128);
    convert_hi_kernel<<<(N_EMB * 128) / 256, 256, 0, stream>>>(w,  Wh, N_EMB * 128);
    wnorm_kernel<<<N_EMB / 4, 256, 0, stream>>>(w, wnorm, cnt);
    dist_mfma_kernel<<<(M_TOK / 128) * (N_EMB / 128), 256, 0, stream>>>(Xh, Wh, wnorm, partials);
    reduce_kernel<<<M_TOK / 256, 256, 0, stream>>>(partials, bestkey, fidx, flaglist, cnt);
    fixup_kernel<<<256, 256, 0, stream>>>(xs, w, wnorm, partials, bestkey, flaglist, cnt, fidx);
    gather_kernel<<<(M_TOK * (D_K / 4)) / 256, 256, 0, stream>>>(xs, w, fidx, out);
  } else {
    float* wnorm = (float*)d_ws;
    float* pval  = wnorm + N_EMB;
    int*   pidx  = (int*)(pval + (size_t)M_TOK * S_SPLIT);
    int*   fidx  = pidx + (size_t)M_TOK * S_SPLIT;
    int*   cnt   = fidx + M_TOK;
    wnorm_kernel<<<N_EMB / 4, 256, 0, stream>>>(w, wnorm, cnt);
    dist_argmin_kernel<<<dim3(M_TOK / BM, S_SPLIT), 256, 0, stream>>>(xs, w, wnorm, pval, pidx);
    reduce_idx_kernel<<<M_TOK / 256, 256, 0, stream>>>(pval, pidx, fidx);
    gather_kernel<<<(M_TOK * (D_K / 4)) / 256, 256, 0, stream>>>(xs, w, fidx, out);
  }
}